// Round 9
// baseline (428.274 us; speedup 1.0000x reference)
//
#include <hip/hip_runtime.h>

// Quantizer via bf16x3-split MFMA GEMM + exact-fp32 recheck of near-ties.
//   x: [16,64,32,32] fp32, embed: [64,8192] fp32
//   out[row][c] = embedT[argmax_j (f_row.e_j - ||e_j||^2/2)][c]
//
// R18: per-CODE top-2 in qdist. R17's grid-barrier fusion cost ~230us in
// atomic-poll contention (dead end); R12-vs-R15 shows dispatch overhead is
// ~2us, so the ~80us tail is real kernel time -- dominated by reduce_rows'
// 1M scattered 4KB-stride x-gathers for the quad rescore. Fix: qdist now
// tracks exact per-code argmax (within-quad argmax + top-2, ascending-j
// ties) and global top-2 code scores. Margin b1-b2 certifies the code-level
// argmax directly -> confident rows in reduce_rows do NO x access and NO
// rescore, just a coalesced eT-row copy. Near-ties still go to recheck.

typedef __attribute__((ext_vector_type(8))) __bf16 bf16x8;
typedef __attribute__((ext_vector_type(4))) float f32x4;
typedef unsigned int u32;
typedef unsigned long long u64;

union frag_cast { f32x4 f; bf16x8 b; };
__device__ __forceinline__ bf16x8 as_bf16x8(f32x4 v) { frag_cast u; u.f = v; return u.b; }

#define N_ROWS  16384
#define E_DIM   64
#define N_EMBED 8192
#define NCHUNK  16
#define COLS_PER_BLOCK (N_EMBED / NCHUNK)   // 512
#define N_ST (COLS_PER_BLOCK / 64)          // 8 stages of 64 codes
#define ROWS_PER_BLOCK 512                  // 4 waves x 128 pixels
#define N_ROWBLK (N_ROWS / ROWS_PER_BLOCK)  // 32
#define NT 8                                // pixel-tiles per wave
#define MARGIN_THR 2e-3f

// ---- workspace byte offsets (~11.4 MB total)
#define WS_AH   0u              // pixel hi  [16384][64] bf16 (2 MB)
#define WS_AL   (2u << 20)      // pixel lo  (2 MB)
#define WS_B    (4u << 20)      // codes: 128 groups x [hi 64x128B | lo 64x128B] (2 MB)
#define WS_ET   (6u << 20)      // embedT fp32 [8192][64] (2 MB)
#define WS_BIAS (8u << 20)      // -||e_j||^2/2 (32 KB)
#define WS_CNT  (WS_BIAS + (32u << 10))     // [0]=nflag
#define WS_PB1  (WS_CNT + (4u << 10))       // 1 MB
#define WS_PI1  (WS_PB1 + (1u << 20))       // 1 MB
#define WS_PB2  (WS_PI1 + (1u << 20))       // 1 MB
#define WS_FLAG (WS_PB2 + (1u << 20))       // 64 KB
#define WS_FKEY (WS_FLAG + (64u << 10))     // 128 KB u64 keys
#define WS_DONE (WS_FKEY + (128u << 10))    // 64 KB per-row seg counters

__device__ __forceinline__ u32 f32_key(float s) {
    u32 u = __float_as_uint(s);
    return (u & 0x80000000u) ? ~u : (u | 0x80000000u);
}

__device__ __forceinline__ void async16(const void* g, void* l) {
    __builtin_amdgcn_global_load_lds(
        (const __attribute__((address_space(1))) void*)g,
        (__attribute__((address_space(3))) void*)l, 16, 0, 0);
}

// ---- K1: prep. Blocks 0..255: split x -> A_hi/A_lo [row][64] bf16.
//          Blocks 256..383: embedT fp32, bias, and swizzled interleaved code groups.
__global__ __launch_bounds__(256) void prep(
        const float* __restrict__ x, const float* __restrict__ embed, char* ws) {
    __shared__ float tile[64][65];
    __bf16* Ah = (__bf16*)(ws + WS_AH);
    __bf16* Al = (__bf16*)(ws + WS_AL);
    float*  eT = (float*)(ws + WS_ET);
    float*  bias = (float*)(ws + WS_BIAS);
    const int t = threadIdx.x;
    const int blk = blockIdx.x;

    if (blk < 256) {
        const int b = blk >> 4, p0 = (blk & 15) * 64;
        {
            const int c = t >> 2, seg = (t & 3) * 16;
            const float* src = x + b * 65536 + c * 1024 + p0 + seg;
#pragma unroll
            for (int i = 0; i < 16; ++i) tile[c][seg + i] = src[i];
        }
        __syncthreads();
        const int p = t >> 2, cq = (t & 3) * 16;
        const long row = b * 1024 + p0 + p;
        bf16x8 vh0, vh1, vl0, vl1;
#pragma unroll
        for (int i = 0; i < 16; ++i) {
            float f = tile[cq + i][p];
            __bf16 h = (__bf16)f;
            __bf16 l = (__bf16)(f - (float)h);
            if (i < 8) { vh0[i] = h; vl0[i] = l; }
            else       { vh1[i - 8] = h; vl1[i - 8] = l; }
        }
        *(bf16x8*)(Ah + row * 64 + cq) = vh0;
        *(bf16x8*)(Ah + row * 64 + cq + 8) = vh1;
        *(bf16x8*)(Al + row * 64 + cq) = vl0;
        *(bf16x8*)(Al + row * 64 + cq + 8) = vl1;
    } else {
        if (blk == 256 && t == 0) *(int*)(ws + WS_CNT) = 0;
        const int g = blk - 256;             // 64-code group
        const int jbase = g * 64;
        char* Bg = ws + WS_B + (size_t)g * 16384;
        {
            const int c = t >> 2, seg = (t & 3) * 16;
            const float* src = embed + c * N_EMBED + jbase + seg;
#pragma unroll
            for (int i = 0; i < 16; ++i) tile[c][seg + i] = src[i];
        }
        __syncthreads();
        if (t < 64) {
            float s = 0.f;
#pragma unroll
            for (int c = 0; c < 64; ++c) { float v = tile[c][t]; s = fmaf(v, v, s); }
            bias[jbase + t] = -0.5f * s;
        }
        const int jl = t >> 2, cq = (t & 3) * 16;   // channels cq..cq+15
        bf16x8 vh0, vh1, vl0, vl1;
#pragma unroll
        for (int i = 0; i < 16; ++i) {
            float f = tile[cq + i][jl];
            eT[(long)(jbase + jl) * 64 + cq + i] = f;
            __bf16 h = (__bf16)f;
            __bf16 l = (__bf16)(f - (float)h);
            if (i < 8) { vh0[i] = h; vl0[i] = l; }
            else       { vh1[i - 8] = h; vl1[i - 8] = l; }
        }
        // granule-XOR swizzle: logical granule k (8 bf16) of code jl stored at
        // position k ^ (jl & 7). Keeps staging contiguous, LDS reads conflict-free.
        const int k0 = (cq >> 3), sw = jl & 7;
        __bf16* hi = (__bf16*)Bg + jl * 64;
        __bf16* lo = (__bf16*)(Bg + 8192) + jl * 64;
        *(bf16x8*)(hi + ((k0 ^ sw) * 8))       = vh0;
        *(bf16x8*)(hi + (((k0 + 1) ^ sw) * 8)) = vh1;
        *(bf16x8*)(lo + ((k0 ^ sw) * 8))       = vl0;
        *(bf16x8*)(lo + (((k0 + 1) ^ sw) * 8)) = vl1;
    }
}

// ---- K2: MFMA GEMM + running per-CODE top-2 argmax (exact index).
// grid 512 blocks (32 rowblk x 16 chunks), 256 thr, 2 blocks/CU.
__global__ __launch_bounds__(256, 2) void qdist(const char* __restrict__ ws_c, char* __restrict__ ws) {
    __shared__ __align__(16) char smem[2][16384];
    const __bf16* Ah = (const __bf16*)(ws_c + WS_AH);
    const __bf16* Al = (const __bf16*)(ws_c + WS_AL);
    const char* Bws = ws_c + WS_B;
    const float* biasg = (const float*)(ws_c + WS_BIAS);
    float* pb1 = (float*)(ws + WS_PB1);
    int*   pi1 = (int*)(ws + WS_PI1);
    float* pb2 = (float*)(ws + WS_PB2);

    const int t = threadIdx.x;
    const int wv = t >> 6, lane = t & 63, ln = lane & 15, q = lane >> 4;
    const int rb = blockIdx.x >> 4, chunk = blockIdx.x & 15;
    const int row0 = rb * ROWS_PER_BLOCK;
    const int col0 = chunk * COLS_PER_BLOCK;
    const int g0 = col0 >> 6;               // first 64-code group of this chunk

    // resident pixel fragments (B-operand): 8 pixel-tiles x 2 K-halves x {hi,lo}
    f32x4 pfh[NT][2], pfl[NT][2];
#pragma unroll
    for (int nt = 0; nt < NT; ++nt) {
        long row = row0 + wv * 128 + nt * 16 + ln;
        long base = row * 64 + q * 8;
        pfh[nt][0] = *(const f32x4*)(Ah + base);
        pfh[nt][1] = *(const f32x4*)(Ah + base + 32);
        pfl[nt][0] = *(const f32x4*)(Al + base);
        pfl[nt][1] = *(const f32x4*)(Al + base + 32);
    }
    asm volatile("" :
        "+v"(pfh[0][0]), "+v"(pfh[0][1]), "+v"(pfh[1][0]), "+v"(pfh[1][1]),
        "+v"(pfh[2][0]), "+v"(pfh[2][1]), "+v"(pfh[3][0]), "+v"(pfh[3][1]),
        "+v"(pfh[4][0]), "+v"(pfh[4][1]), "+v"(pfh[5][0]), "+v"(pfh[5][1]),
        "+v"(pfh[6][0]), "+v"(pfh[6][1]), "+v"(pfh[7][0]), "+v"(pfh[7][1]));
    asm volatile("" :
        "+v"(pfl[0][0]), "+v"(pfl[0][1]), "+v"(pfl[1][0]), "+v"(pfl[1][1]),
        "+v"(pfl[2][0]), "+v"(pfl[2][1]), "+v"(pfl[3][0]), "+v"(pfl[3][1]),
        "+v"(pfl[4][0]), "+v"(pfl[4][1]), "+v"(pfl[5][0]), "+v"(pfl[5][1]),
        "+v"(pfl[6][0]), "+v"(pfl[6][1]), "+v"(pfl[7][0]), "+v"(pfl[7][1]));

    float b1[NT], b2[NT]; int iq[NT];
#pragma unroll
    for (int k = 0; k < NT; ++k) { b1[k] = -3.4e38f; b2[k] = -3.4e38f; iq[k] = 0; }

    // swizzled fragment read offsets: code cl=ct*16+ln; hi-K0 granule q^(ln&7)
    const int s7 = ln & 7;
    const int rdbase = ln * 128 + ((q ^ s7) << 4);

    auto issue = [&](int st) {
        const char* src = Bws + (size_t)(g0 + st) * 16384;
        char* dst = smem[st & 1];
#pragma unroll
        for (int s = 0; s < 4; ++s)
            async16(src + s * 4096 + wv * 1024 + lane * 16,
                    dst + s * 4096 + wv * 1024);
    };

    issue(0);
    for (int st = 0; st < N_ST; ++st) {
        __syncthreads();                 // own staging drained (vmcnt0 before barrier);
        if (st + 1 < N_ST) issue(st + 1);// all waves done reading buf[(st+1)&1]
        const char* buf = smem[st & 1];
        __builtin_amdgcn_s_setprio(1);
#pragma unroll
        for (int ct = 0; ct < 4; ++ct) {
            const int boff = ct * 2048 + rdbase;
            bf16x8 ah0 = *(const bf16x8*)(buf + boff);
            bf16x8 ah1 = *(const bf16x8*)(buf + (boff ^ 64));
            bf16x8 al0 = *(const bf16x8*)(buf + 8192 + boff);
            bf16x8 al1 = *(const bf16x8*)(buf + 8192 + (boff ^ 64));
            const int cbase = col0 + st * 64 + ct * 16;
            f32x4 bv = *(const f32x4*)(biasg + cbase + q * 4);  // bias for 4 codes
            const int jq = cbase + q * 4;
#pragma unroll
            for (int nt = 0; nt < NT; ++nt) {
                f32x4 acc = __builtin_amdgcn_mfma_f32_16x16x32_bf16(al0, as_bf16x8(pfh[nt][0]), bv, 0, 0, 0);
                acc = __builtin_amdgcn_mfma_f32_16x16x32_bf16(al1, as_bf16x8(pfh[nt][1]), acc, 0, 0, 0);
                acc = __builtin_amdgcn_mfma_f32_16x16x32_bf16(ah0, as_bf16x8(pfl[nt][0]), acc, 0, 0, 0);
                acc = __builtin_amdgcn_mfma_f32_16x16x32_bf16(ah1, as_bf16x8(pfl[nt][1]), acc, 0, 0, 0);
                acc = __builtin_amdgcn_mfma_f32_16x16x32_bf16(ah0, as_bf16x8(pfh[nt][0]), acc, 0, 0, 0);
                acc = __builtin_amdgcn_mfma_f32_16x16x32_bf16(ah1, as_bf16x8(pfh[nt][1]), acc, 0, 0, 0);
                // within-quad argmax (ascending-j ties) + top-2 of the 4 codes
                float m01 = fmaxf(acc[0], acc[1]);
                float m23 = fmaxf(acc[2], acc[3]);
                float m1q = fmaxf(m01, m23);
                float m2q = fmaxf(fminf(m01, m23),
                                  fmaxf(fminf(acc[0], acc[1]), fminf(acc[2], acc[3])));
                int iql = (m23 > m01) ? ((acc[3] > acc[2]) ? 3 : 2)
                                      : ((acc[1] > acc[0]) ? 1 : 0);
                // global per-code top-2 merge
                b2[nt] = fmaxf(fmaxf(fminf(b1[nt], m1q), b2[nt]), m2q);
                bool gt = m1q > b1[nt];
                b1[nt] = fmaxf(b1[nt], m1q);
                iq[nt] = gt ? (jq + iql) : iq[nt];
            }
        }
        __builtin_amdgcn_s_setprio(0);
    }

    // merge across the 4 quads (same pixel lives in lanes ln, ln+16, ln+32, ln+48)
#pragma unroll
    for (int m = 16; m < 64; m <<= 1) {
#pragma unroll
        for (int nt = 0; nt < NT; ++nt) {
            float o1 = __shfl_xor(b1[nt], m);
            int   oi = __shfl_xor(iq[nt], m);
            float o2 = __shfl_xor(b2[nt], m);
            b2[nt] = fmaxf(fmaxf(fminf(b1[nt], o1), o2), b2[nt]);
            bool take = (o1 > b1[nt]) || (o1 == b1[nt] && oi < iq[nt]);
            if (take) { b1[nt] = o1; iq[nt] = oi; }
        }
    }
    if (q == 0) {
#pragma unroll
        for (int nt = 0; nt < NT; ++nt) {
            int pixel = row0 + wv * 128 + nt * 16 + ln;
            int o = chunk * N_ROWS + pixel;
            pb1[o] = b1[nt];
            pi1[o] = iq[nt];
            pb2[o] = b2[nt];
        }
    }
}

// ---- K3: merge chunks per row, 4 lanes/row. Confident rows: direct coalesced
// eT-row copy (index already exact). Near-ties: flag for recheck.
// 256 blocks x 256 thr (4 waves/CU).
__global__ __launch_bounds__(256) void reduce_rows(char* ws, float* __restrict__ out) {
    const float* pb1 = (const float*)(ws + WS_PB1);
    const int*   pi1 = (const int*)(ws + WS_PI1);
    const float* pb2 = (const float*)(ws + WS_PB2);
    const float* eT = (const float*)(ws + WS_ET);
    int* flags = (int*)(ws + WS_FLAG);
    int* cnt = (int*)(ws + WS_CNT);
    u64* fkey = (u64*)(ws + WS_FKEY);
    int* done = (int*)(ws + WS_DONE);
    const int t = threadIdx.x;
    const int row = (blockIdx.x * 256 + t) >> 2;
    const int sub = t & 3;

    // per-lane merge over chunks sub*4 .. sub*4+3 (coalesced across the wave)
    float m1 = -3.4e38f, m2 = -3.4e38f; int mi = 0;
#pragma unroll
    for (int k = 0; k < 4; ++k) {
        const int ch = sub * 4 + k;
        float o1 = pb1[ch * N_ROWS + row];
        int   oi = pi1[ch * N_ROWS + row];
        float o2 = pb2[ch * N_ROWS + row];
        m2 = fmaxf(fmaxf(fminf(m1, o1), o2), m2);
        if (o1 > m1 || (o1 == m1 && oi < mi)) { m1 = o1; mi = oi; }
    }
    // merge across the 4 lanes of this row (xor masks 1,2 stay in-group)
#pragma unroll
    for (int m = 1; m < 4; m <<= 1) {
        float o1 = __shfl_xor(m1, m);
        int   oi = __shfl_xor(mi, m);
        float o2 = __shfl_xor(m2, m);
        m2 = fmaxf(fmaxf(fminf(m1, o1), o2), m2);
        bool take = (o1 > m1) || (o1 == m1 && oi < mi);
        if (take) { m1 = o1; mi = oi; }
    }

    if (m1 - m2 < MARGIN_THR) {
        if (sub == 0) {
            fkey[row] = 0ull;                  // any finite score key > 0
            done[row] = 0;
            flags[atomicAdd(cnt, 1)] = row;    // out written by recheck
        }
    } else {
        // index is exact: coalesced row copy, 4 lanes x 4 f32x4
        const f32x4* src = (const f32x4*)(eT + (size_t)mi * 64);
        f32x4* dst = (f32x4*)(out + (size_t)row * 64);
#pragma unroll
        for (int v = 0; v < 4; ++v) dst[v * 4 + sub] = src[v * 4 + sub];
    }
}

// ---- K4: exact fp32 rescan of flagged rows, 32 segment-blocks/row x 256 codes.
// The 32nd segment block per row decodes fkey and writes the output row.
__global__ __launch_bounds__(256) void recheck(const float* __restrict__ x, char* ws,
                                               float* __restrict__ out) {
    __shared__ float fl[64];
    __shared__ u64 red[256];
    __shared__ int sLast, sIdx;
    const float* eT = (const float*)(ws + WS_ET);
    const float* bias = (const float*)(ws + WS_BIAS);
    const int* flags = (const int*)(ws + WS_FLAG);
    const int n = *(const int*)(ws + WS_CNT);
    u64* fkey = (u64*)(ws + WS_FKEY);
    int* done = (int*)(ws + WS_DONE);
    const int t = threadIdx.x;

    for (int e = blockIdx.x; e < n * 32; e += gridDim.x) {
        const int row = flags[e >> 5];
        const int seg = e & 31;
        __syncthreads();                          // protect fl/red reuse
        if (t < 64) fl[t] = x[(row >> 10) * 65536 + t * 1024 + (row & 1023)];
        __syncthreads();
        float xr[64];
#pragma unroll
        for (int c = 0; c < 64; ++c) xr[c] = fl[c];

        const int j = seg * 256 + t;              // this thread's code
        const f32x4* ecd = (const f32x4*)(eT + (size_t)j * 64);
        f32x4 a0 = {0.f, 0.f, 0.f, 0.f}, a1 = a0, a2 = a0, a3 = a0;
#pragma unroll
        for (int v = 0; v < 4; ++v) {
            f32x4 e0 = ecd[v * 4 + 0], e1 = ecd[v * 4 + 1];
            f32x4 e2 = ecd[v * 4 + 2], e3 = ecd[v * 4 + 3];
#pragma unroll
            for (int k = 0; k < 4; ++k) {
                a0[k] = fmaf(xr[v * 16 + k],      e0[k], a0[k]);
                a1[k] = fmaf(xr[v * 16 + 4 + k],  e1[k], a1[k]);
                a2[k] = fmaf(xr[v * 16 + 8 + k],  e2[k], a2[k]);
                a3[k] = fmaf(xr[v * 16 + 12 + k], e3[k], a3[k]);
            }
        }
        f32x4 a01 = a0 + a1, a23 = a2 + a3;
        f32x4 as = a01 + a23;
        float s = bias[j] + ((as[0] + as[1]) + (as[2] + as[3]));

        red[t] = ((u64)f32_key(s) << 32) | (u32)(~(u32)j);
        __syncthreads();
        for (int off = 128; off; off >>= 1) {
            if (t < off) { u64 o = red[t + off]; if (o > red[t]) red[t] = o; }
            __syncthreads();
        }
        if (t == 0) {
            atomicMax(&fkey[row], red[0]);
            __threadfence();
            sLast = (atomicAdd(&done[row], 1) == 31) ? 1 : 0;
        }
        __syncthreads();
        if (sLast) {                               // block-uniform
            if (t == 0) {
                u64 k = atomicMax(&fkey[row], 0ull);   // coherent read
                sIdx = (int)(~(u32)(k & 0xffffffffull));
            }
            __syncthreads();
            if (t < 64) out[(size_t)row * 64 + t] = eT[(size_t)sIdx * 64 + t];
        }
        __syncthreads();
    }
}

extern "C" void kernel_launch(void* const* d_in, const int* in_sizes, int n_in,
                              void* d_out, int out_size, void* d_ws, size_t ws_size,
                              hipStream_t stream) {
    const float* x     = (const float*)d_in[0];
    const float* embed = (const float*)d_in[1];
    float* out = (float*)d_out;
    char* ws = (char*)d_ws;

    prep<<<384, 256, 0, stream>>>(x, embed, ws);
    qdist<<<N_ROWBLK * NCHUNK, 256, 0, stream>>>(ws, ws);
    reduce_rows<<<256, 256, 0, stream>>>(ws, out);
    recheck<<<2048, 256, 0, stream>>>(x, ws, out);
}

// Round 10
// 130.224 us; speedup vs baseline: 3.2887x; 3.2887x over previous
//
#include <hip/hip_runtime.h>

// Quantizer via bf16x3-split MFMA GEMM + exact-fp32 recheck of near-ties.
//   x: [16,64,32,32] fp32, embed: [64,8192] fp32
//   out[row][c] = embedT[argmax_j (f_row.e_j - ||e_j||^2/2)][c]
//
// R19: delete the recheck DISPATCH. Round-total algebra: floor+prep ~52us
// (R17), recheck ~13.5us (R14), reduce_rows ~14us (R15); qdist 49.3.
// R18's per-code argmax spilled the pf fragment arrays (1GB scratch traffic,
// 357us) -> qdist reverted byte-for-byte to R15. reduce_rows now inlines the
// exact rescan of flagged rows as a rare wave-cooperative path: ballot the
// flagged rows, whole wave rescans chunks with pb1 >= b1 - 2*THR (same
// eps<=THR/2 assumption the margin test always used, 2x slack), 8 codes/lane,
// x broadcast via shfl (no LDS/syncthreads -> divergence-safe). 3 dispatches.

typedef __attribute__((ext_vector_type(8))) __bf16 bf16x8;
typedef __attribute__((ext_vector_type(4))) float f32x4;
typedef unsigned int u32;
typedef unsigned long long u64;

union frag_cast { f32x4 f; bf16x8 b; };
__device__ __forceinline__ bf16x8 as_bf16x8(f32x4 v) { frag_cast u; u.f = v; return u.b; }

#define N_ROWS  16384
#define E_DIM   64
#define N_EMBED 8192
#define NCHUNK  16
#define COLS_PER_BLOCK (N_EMBED / NCHUNK)   // 512
#define N_ST (COLS_PER_BLOCK / 64)          // 8 stages of 64 codes
#define ROWS_PER_BLOCK 512                  // 4 waves x 128 pixels
#define N_ROWBLK (N_ROWS / ROWS_PER_BLOCK)  // 32
#define NT 8                                // pixel-tiles per wave
#define MARGIN_THR 2e-3f

// ---- workspace byte offsets (~11.3 MB total)
#define WS_AH   0u              // pixel hi  [16384][64] bf16 (2 MB)
#define WS_AL   (2u << 20)      // pixel lo  (2 MB)
#define WS_B    (4u << 20)      // codes: 128 groups x [hi 64x128B | lo 64x128B] (2 MB)
#define WS_ET   (6u << 20)      // embedT fp32 [8192][64] (2 MB)
#define WS_BIAS (8u << 20)      // -||e_j||^2/2 (32 KB)
#define WS_CNT  (WS_BIAS + (32u << 10))     // (unused scratch)
#define WS_PB1  (WS_CNT + (4u << 10))       // 1 MB
#define WS_PI1  (WS_PB1 + (1u << 20))       // 1 MB
#define WS_PB2  (WS_PI1 + (1u << 20))       // 1 MB

__device__ __forceinline__ u32 f32_key(float s) {
    u32 u = __float_as_uint(s);
    return (u & 0x80000000u) ? ~u : (u | 0x80000000u);
}

__device__ __forceinline__ void async16(const void* g, void* l) {
    __builtin_amdgcn_global_load_lds(
        (const __attribute__((address_space(1))) void*)g,
        (__attribute__((address_space(3))) void*)l, 16, 0, 0);
}

// ---- K1: prep. Blocks 0..255: split x -> A_hi/A_lo [row][64] bf16.
//          Blocks 256..383: embedT fp32, bias, and swizzled interleaved code groups.
__global__ __launch_bounds__(256) void prep(
        const float* __restrict__ x, const float* __restrict__ embed, char* ws) {
    __shared__ float tile[64][65];
    __bf16* Ah = (__bf16*)(ws + WS_AH);
    __bf16* Al = (__bf16*)(ws + WS_AL);
    float*  eT = (float*)(ws + WS_ET);
    float*  bias = (float*)(ws + WS_BIAS);
    const int t = threadIdx.x;
    const int blk = blockIdx.x;

    if (blk < 256) {
        const int b = blk >> 4, p0 = (blk & 15) * 64;
        {
            const int c = t >> 2, seg = (t & 3) * 16;
            const float* src = x + b * 65536 + c * 1024 + p0 + seg;
#pragma unroll
            for (int i = 0; i < 16; ++i) tile[c][seg + i] = src[i];
        }
        __syncthreads();
        const int p = t >> 2, cq = (t & 3) * 16;
        const long row = b * 1024 + p0 + p;
        bf16x8 vh0, vh1, vl0, vl1;
#pragma unroll
        for (int i = 0; i < 16; ++i) {
            float f = tile[cq + i][p];
            __bf16 h = (__bf16)f;
            __bf16 l = (__bf16)(f - (float)h);
            if (i < 8) { vh0[i] = h; vl0[i] = l; }
            else       { vh1[i - 8] = h; vl1[i - 8] = l; }
        }
        *(bf16x8*)(Ah + row * 64 + cq) = vh0;
        *(bf16x8*)(Ah + row * 64 + cq + 8) = vh1;
        *(bf16x8*)(Al + row * 64 + cq) = vl0;
        *(bf16x8*)(Al + row * 64 + cq + 8) = vl1;
    } else {
        const int g = blk - 256;             // 64-code group
        const int jbase = g * 64;
        char* Bg = ws + WS_B + (size_t)g * 16384;
        {
            const int c = t >> 2, seg = (t & 3) * 16;
            const float* src = embed + c * N_EMBED + jbase + seg;
#pragma unroll
            for (int i = 0; i < 16; ++i) tile[c][seg + i] = src[i];
        }
        __syncthreads();
        if (t < 64) {
            float s = 0.f;
#pragma unroll
            for (int c = 0; c < 64; ++c) { float v = tile[c][t]; s = fmaf(v, v, s); }
            bias[jbase + t] = -0.5f * s;
        }
        const int jl = t >> 2, cq = (t & 3) * 16;   // channels cq..cq+15
        bf16x8 vh0, vh1, vl0, vl1;
#pragma unroll
        for (int i = 0; i < 16; ++i) {
            float f = tile[cq + i][jl];
            eT[(long)(jbase + jl) * 64 + cq + i] = f;
            __bf16 h = (__bf16)f;
            __bf16 l = (__bf16)(f - (float)h);
            if (i < 8) { vh0[i] = h; vl0[i] = l; }
            else       { vh1[i - 8] = h; vl1[i - 8] = l; }
        }
        // granule-XOR swizzle: logical granule k (8 bf16) of code jl stored at
        // position k ^ (jl & 7). Keeps staging contiguous, LDS reads conflict-free.
        const int k0 = (cq >> 3), sw = jl & 7;
        __bf16* hi = (__bf16*)Bg + jl * 64;
        __bf16* lo = (__bf16*)(Bg + 8192) + jl * 64;
        *(bf16x8*)(hi + ((k0 ^ sw) * 8))       = vh0;
        *(bf16x8*)(hi + (((k0 + 1) ^ sw) * 8)) = vh1;
        *(bf16x8*)(lo + ((k0 ^ sw) * 8))       = vl0;
        *(bf16x8*)(lo + (((k0 + 1) ^ sw) * 8)) = vl1;
    }
}

// ---- K2: MFMA GEMM + running (quad-max top-2) argmax (proven R9/R15 bytes).
// grid 512 blocks (32 rowblk x 16 chunks), 256 thr, 2 blocks/CU.
__global__ __launch_bounds__(256, 2) void qdist(const char* __restrict__ ws_c, char* __restrict__ ws) {
    __shared__ __align__(16) char smem[2][16384];
    const __bf16* Ah = (const __bf16*)(ws_c + WS_AH);
    const __bf16* Al = (const __bf16*)(ws_c + WS_AL);
    const char* Bws = ws_c + WS_B;
    const float* biasg = (const float*)(ws_c + WS_BIAS);
    float* pb1 = (float*)(ws + WS_PB1);
    int*   pi1 = (int*)(ws + WS_PI1);
    float* pb2 = (float*)(ws + WS_PB2);

    const int t = threadIdx.x;
    const int wv = t >> 6, lane = t & 63, ln = lane & 15, q = lane >> 4;
    const int rb = blockIdx.x >> 4, chunk = blockIdx.x & 15;
    const int row0 = rb * ROWS_PER_BLOCK;
    const int col0 = chunk * COLS_PER_BLOCK;
    const int g0 = col0 >> 6;               // first 64-code group of this chunk

    // resident pixel fragments (B-operand): 8 pixel-tiles x 2 K-halves x {hi,lo}
    f32x4 pfh[NT][2], pfl[NT][2];
#pragma unroll
    for (int nt = 0; nt < NT; ++nt) {
        long row = row0 + wv * 128 + nt * 16 + ln;
        long base = row * 64 + q * 8;
        pfh[nt][0] = *(const f32x4*)(Ah + base);
        pfh[nt][1] = *(const f32x4*)(Ah + base + 32);
        pfl[nt][0] = *(const f32x4*)(Al + base);
        pfl[nt][1] = *(const f32x4*)(Al + base + 32);
    }
    asm volatile("" :
        "+v"(pfh[0][0]), "+v"(pfh[0][1]), "+v"(pfh[1][0]), "+v"(pfh[1][1]),
        "+v"(pfh[2][0]), "+v"(pfh[2][1]), "+v"(pfh[3][0]), "+v"(pfh[3][1]),
        "+v"(pfh[4][0]), "+v"(pfh[4][1]), "+v"(pfh[5][0]), "+v"(pfh[5][1]),
        "+v"(pfh[6][0]), "+v"(pfh[6][1]), "+v"(pfh[7][0]), "+v"(pfh[7][1]));
    asm volatile("" :
        "+v"(pfl[0][0]), "+v"(pfl[0][1]), "+v"(pfl[1][0]), "+v"(pfl[1][1]),
        "+v"(pfl[2][0]), "+v"(pfl[2][1]), "+v"(pfl[3][0]), "+v"(pfl[3][1]),
        "+v"(pfl[4][0]), "+v"(pfl[4][1]), "+v"(pfl[5][0]), "+v"(pfl[5][1]),
        "+v"(pfl[6][0]), "+v"(pfl[6][1]), "+v"(pfl[7][0]), "+v"(pfl[7][1]));

    float b1[NT], b2[NT]; int iq[NT];
#pragma unroll
    for (int k = 0; k < NT; ++k) { b1[k] = -3.4e38f; b2[k] = -3.4e38f; iq[k] = 0; }

    // swizzled fragment read offsets: code cl=ct*16+ln; hi-K0 granule q^(ln&7)
    const int s7 = ln & 7;
    const int rdbase = ln * 128 + ((q ^ s7) << 4);

    auto issue = [&](int st) {
        const char* src = Bws + (size_t)(g0 + st) * 16384;
        char* dst = smem[st & 1];
#pragma unroll
        for (int s = 0; s < 4; ++s)
            async16(src + s * 4096 + wv * 1024 + lane * 16,
                    dst + s * 4096 + wv * 1024);
    };

    issue(0);
    for (int st = 0; st < N_ST; ++st) {
        __syncthreads();                 // own staging drained (vmcnt0 before barrier);
        if (st + 1 < N_ST) issue(st + 1);// all waves done reading buf[(st+1)&1]
        const char* buf = smem[st & 1];
        __builtin_amdgcn_s_setprio(1);
#pragma unroll
        for (int ct = 0; ct < 4; ++ct) {
            const int boff = ct * 2048 + rdbase;
            bf16x8 ah0 = *(const bf16x8*)(buf + boff);
            bf16x8 ah1 = *(const bf16x8*)(buf + (boff ^ 64));
            bf16x8 al0 = *(const bf16x8*)(buf + 8192 + boff);
            bf16x8 al1 = *(const bf16x8*)(buf + 8192 + (boff ^ 64));
            const int cbase = col0 + st * 64 + ct * 16;
            f32x4 bv = *(const f32x4*)(biasg + cbase + q * 4);  // bias for 4 codes
            const int jq = cbase + q * 4;
#pragma unroll
            for (int nt = 0; nt < NT; ++nt) {
                f32x4 acc = __builtin_amdgcn_mfma_f32_16x16x32_bf16(al0, as_bf16x8(pfh[nt][0]), bv, 0, 0, 0);
                acc = __builtin_amdgcn_mfma_f32_16x16x32_bf16(al1, as_bf16x8(pfh[nt][1]), acc, 0, 0, 0);
                acc = __builtin_amdgcn_mfma_f32_16x16x32_bf16(ah0, as_bf16x8(pfl[nt][0]), acc, 0, 0, 0);
                acc = __builtin_amdgcn_mfma_f32_16x16x32_bf16(ah1, as_bf16x8(pfl[nt][1]), acc, 0, 0, 0);
                acc = __builtin_amdgcn_mfma_f32_16x16x32_bf16(ah0, as_bf16x8(pfh[nt][0]), acc, 0, 0, 0);
                acc = __builtin_amdgcn_mfma_f32_16x16x32_bf16(ah1, as_bf16x8(pfh[nt][1]), acc, 0, 0, 0);
                // quad max (4 codes of one pixel)
                float mx = fmaxf(fmaxf(acc[0], acc[1]), fmaxf(acc[2], acc[3]));
                b2[nt] = fmaxf(b2[nt], fminf(b1[nt], mx));
                bool gt = mx > b1[nt];
                b1[nt] = fmaxf(b1[nt], mx);
                iq[nt] = gt ? jq : iq[nt];
            }
        }
        __builtin_amdgcn_s_setprio(0);
    }

    // merge across the 4 quads (same pixel lives in lanes ln, ln+16, ln+32, ln+48)
#pragma unroll
    for (int m = 16; m < 64; m <<= 1) {
#pragma unroll
        for (int nt = 0; nt < NT; ++nt) {
            float o1 = __shfl_xor(b1[nt], m);
            int   oi = __shfl_xor(iq[nt], m);
            float o2 = __shfl_xor(b2[nt], m);
            b2[nt] = fmaxf(fmaxf(fminf(b1[nt], o1), o2), b2[nt]);
            bool take = (o1 > b1[nt]) || (o1 == b1[nt] && oi < iq[nt]);
            if (take) { b1[nt] = o1; iq[nt] = oi; }
        }
    }
    if (q == 0) {
#pragma unroll
        for (int nt = 0; nt < NT; ++nt) {
            int pixel = row0 + wv * 128 + nt * 16 + ln;
            int o = chunk * N_ROWS + pixel;
            pb1[o] = b1[nt];
            pi1[o] = iq[nt];
            pb2[o] = b2[nt];
        }
    }
}

// ---- K3: merge chunks per row (4 lanes/row) + exact quad rescore for
// confident rows + INLINE wave-cooperative rescan for flagged rows.
// 256 blocks x 256 thr (4 waves/CU). No __syncthreads (divergence-safe).
__global__ __launch_bounds__(256) void reduce_rows(const float* __restrict__ x, char* ws,
                                                   float* __restrict__ out) {
    const float* pb1 = (const float*)(ws + WS_PB1);
    const int*   pi1 = (const int*)(ws + WS_PI1);
    const float* pb2 = (const float*)(ws + WS_PB2);
    const float* eT = (const float*)(ws + WS_ET);
    const float* bias = (const float*)(ws + WS_BIAS);
    const int t = threadIdx.x;
    const int lane = t & 63, wv = t >> 6;
    const int row = (blockIdx.x * 256 + t) >> 2;
    const int sub = t & 3;

    // per-lane merge over chunks sub*4 .. sub*4+3 (coalesced across the wave)
    float m1 = -3.4e38f, m2 = -3.4e38f; int mi = 0;
#pragma unroll
    for (int k = 0; k < 4; ++k) {
        const int ch = sub * 4 + k;
        float o1 = pb1[ch * N_ROWS + row];
        int   oi = pi1[ch * N_ROWS + row];
        float o2 = pb2[ch * N_ROWS + row];
        m2 = fmaxf(fmaxf(fminf(m1, o1), o2), m2);
        if (o1 > m1 || (o1 == m1 && oi < mi)) { m1 = o1; mi = oi; }
    }
    // merge across the 4 lanes of this row (xor masks 1,2 stay in-group)
#pragma unroll
    for (int m = 1; m < 4; m <<= 1) {
        float o1 = __shfl_xor(m1, m);
        int   oi = __shfl_xor(mi, m);
        float o2 = __shfl_xor(m2, m);
        m2 = fmaxf(fmaxf(fminf(m1, o1), o2), m2);
        bool take = (o1 > m1) || (o1 == m1 && oi < mi);
        if (take) { m1 = o1; mi = oi; }
    }

    const bool flagged = (m1 - m2 < MARGIN_THR);   // uniform across row's 4 lanes
    if (!flagged) {
        // exact fp32 rescore of winning quad: lane sub scores code mi+sub
        const float* xb = x + (row >> 10) * 65536 + (row & 1023);
        const int j = mi + sub;
        const f32x4* ecd = (const f32x4*)(eT + (size_t)j * 64);
        float s = bias[j];
#pragma unroll
        for (int v = 0; v < 16; ++v) {
            f32x4 ev = ecd[v];
            s = fmaf(xb[(v * 4 + 0) * 1024], ev[0], s);
            s = fmaf(xb[(v * 4 + 1) * 1024], ev[1], s);
            s = fmaf(xb[(v * 4 + 2) * 1024], ev[2], s);
            s = fmaf(xb[(v * 4 + 3) * 1024], ev[3], s);
        }
        // argmax across the 4 lanes; tie -> lowest j
        float best = s; int bj = j;
#pragma unroll
        for (int m = 1; m < 4; m <<= 1) {
            float os = __shfl_xor(best, m);
            int   oj = __shfl_xor(bj, m);
            bool take = (os > best) || (os == best && oj < bj);
            if (take) { best = os; bj = oj; }
        }
        // cooperative row write: 4 lanes x 4 f32x4
        const f32x4* src = (const f32x4*)(eT + (size_t)bj * 64);
        f32x4* dst = (f32x4*)(out + (size_t)row * 64);
#pragma unroll
        for (int v = 0; v < 4; ++v) dst[v * 4 + sub] = src[v * 4 + sub];
    }

    // ---- rare path: whole wave rescans each flagged row of its 16 rows ----
    u64 bal = __ballot(flagged);
    const int wrow0 = blockIdx.x * 64 + wv * 16;     // first row of this wave
    while (bal) {
        const int b = __ffsll(bal) - 1;
        const int rw = b >> 2;
        bal &= ~(0xFull << (rw * 4));
        const int r = wrow0 + rw;
        const float rb1 = __shfl(m1, rw * 4);        // row's merged approx max
        const float cutoff = rb1 - 2.0f * MARGIN_THR;

        // broadcast the x row: lane c loads channel c, then shfl to all lanes
        float xv = x[(r >> 10) * 65536 + lane * 1024 + (r & 1023)];
        float xr[64];
#pragma unroll
        for (int c = 0; c < 64; ++c) xr[c] = __shfl(xv, c);

        u64 bestk = 0ull;
        for (int ch = 0; ch < NCHUNK; ++ch) {
            // any code that could truly win has approx >= rb1 - 2*eps, and its
            // chunk max pb1 >= that; cutoff uses 2*THR (2x slack vs the same
            // eps<=THR/2 assumption the margin test relies on).
            if (pb1[ch * N_ROWS + r] < cutoff) continue;   // wave-uniform branch
#pragma unroll
            for (int k = 0; k < 8; ++k) {
                const int j = ch * 512 + lane * 8 + k;
                const f32x4* ecd = (const f32x4*)(eT + (size_t)j * 64);
                f32x4 a0 = {0.f, 0.f, 0.f, 0.f}, a1 = a0, a2 = a0, a3 = a0;
#pragma unroll
                for (int v = 0; v < 4; ++v) {
                    f32x4 e0 = ecd[v * 4 + 0], e1 = ecd[v * 4 + 1];
                    f32x4 e2 = ecd[v * 4 + 2], e3 = ecd[v * 4 + 3];
#pragma unroll
                    for (int kk = 0; kk < 4; ++kk) {
                        a0[kk] = fmaf(xr[v * 16 + kk],      e0[kk], a0[kk]);
                        a1[kk] = fmaf(xr[v * 16 + 4 + kk],  e1[kk], a1[kk]);
                        a2[kk] = fmaf(xr[v * 16 + 8 + kk],  e2[kk], a2[kk]);
                        a3[kk] = fmaf(xr[v * 16 + 12 + kk], e3[kk], a3[kk]);
                    }
                }
                f32x4 a01 = a0 + a1, a23 = a2 + a3;
                f32x4 as = a01 + a23;
                float s = bias[j] + ((as[0] + as[1]) + (as[2] + as[3]));
                u64 key = ((u64)f32_key(s) << 32) | (u32)(~(u32)j);
                bestk = (key > bestk) ? key : bestk;
            }
        }
        // wave-wide max (all lanes end with the same key)
#pragma unroll
        for (int m = 1; m < 64; m <<= 1) {
            u64 o = __shfl_xor(bestk, m);
            bestk = (o > bestk) ? o : bestk;
        }
        const int idx = (int)(~(u32)(bestk & 0xffffffffull));
        out[(size_t)r * 64 + lane] = eT[(size_t)idx * 64 + lane];
    }
}

extern "C" void kernel_launch(void* const* d_in, const int* in_sizes, int n_in,
                              void* d_out, int out_size, void* d_ws, size_t ws_size,
                              hipStream_t stream) {
    const float* x     = (const float*)d_in[0];
    const float* embed = (const float*)d_in[1];
    float* out = (float*)d_out;
    char* ws = (char*)d_ws;

    prep<<<384, 256, 0, stream>>>(x, embed, ws);
    qdist<<<N_ROWBLK * NCHUNK, 256, 0, stream>>>(ws, ws);
    reduce_rows<<<256, 256, 0, stream>>>(x, ws, out);
}